// Round 18
// baseline (265.294 us; speedup 1.0000x reference)
//
#include <hip/hip_runtime.h>
#include <hip/hip_fp16.h>
#include <stdint.h>
#include <math.h>

#define B_  4
#define N_  1024
#define D_  512
#define H_  8
#define HD_ 64

typedef short s16x8 __attribute__((ext_vector_type(8)));
typedef float f32x4 __attribute__((ext_vector_type(4)));
typedef float f32x2 __attribute__((ext_vector_type(2)));
typedef __fp16 f16x2 __attribute__((ext_vector_type(2)));   // matches cvt_pkrtz / fdot2

typedef const __attribute__((address_space(1))) void* gas1p;
typedef __attribute__((address_space(3))) void* las3p;
__device__ __forceinline__ void gload16(const void* g, void* l) {
    __builtin_amdgcn_global_load_lds((gas1p)g, (las3p)l, 16, 0, 0);
}

__device__ __forceinline__ unsigned short f2bf(float f) {
    unsigned u = __float_as_uint(f);
    u += 0x7fffu + ((u >> 16) & 1u);      // RNE
    return (unsigned short)(u >> 16);
}
__device__ __forceinline__ float bf2f(unsigned short h) {
    return __uint_as_float(((unsigned)h) << 16);
}

// fast exact-erf gelu: A&S 7.1.26 rational, |erf err| <= 1.5e-7, branch-free
__device__ __forceinline__ float fast_gelu(float x) {
    float ax = fabsf(x) * 0.7071067811865476f;          // |x|/sqrt(2)
    float t  = __builtin_amdgcn_rcpf(fmaf(0.3275911f, ax, 1.0f));
    float e  = __expf(-ax * ax);
    float poly = t * fmaf(t, fmaf(t, fmaf(t, fmaf(t, 1.061405429f, -1.453152027f),
                                          1.421413741f), -0.284496736f), 0.254829592f);
    float erfv = 1.0f - poly * e;                        // erf(|x|/sqrt2)
    float s = copysignf(erfv, x);
    return 0.5f * x * (1.0f + s);
}

// ---------------- split f32 -> (hi, lo) bf16 ----------------
__global__ void k_split(const float* __restrict__ s, unsigned short* __restrict__ h,
                        unsigned short* __restrict__ l, int n) {
    int i = blockIdx.x * 256 + threadIdx.x;
    if (i < n) {
        float x = s[i];
        unsigned short hb = f2bf(x);
        h[i] = hb;
        l[i] = f2bf(x - bf2f(hb));
    }
}

// ---------------- mask layout detection ----------------
__global__ void k_mask_detect(const unsigned char* __restrict__ m, int* __restrict__ flag) {
    __shared__ int s;
    if (threadIdx.x == 0) s = 0;
    __syncthreads();
    int found = 0;
    for (int i = threadIdx.x; i < B_ * N_; i += 256)
        if ((i & 3) && m[i]) found = 1;
    if (found) atomicOr(&s, 1);
    __syncthreads();
    if (threadIdx.x == 0) flag[0] = s;
}

// ---------------- split-bf16 GEMM: C[M,N] = A[M,K] @ B[N,K]^T (+bias) ----------------
// Staging via global_load_lds (16B DMA): no reg round-trip, no address VALU.
__global__ __launch_bounds__(256) void k_gemm3(
    const unsigned short* __restrict__ Ah, const unsigned short* __restrict__ Al,
    const unsigned short* __restrict__ Bwh, const unsigned short* __restrict__ Bwl,
    float* __restrict__ C, const float* __restrict__ bias, int M, int Nn, int K)
{
    constexpr int BM = 64, BN = 128, BK = 64;
    __shared__ unsigned short At[BM * BK];
    __shared__ unsigned short Bt[BN * BK];
    const int tid = threadIdx.x, lane = tid & 63, wid = tid >> 6;
    const int m0 = blockIdx.x * BM, n0 = blockIdx.y * BN;
    const int wm = wid >> 1, wn = wid & 1;   // wave tile: 32 rows x 64 cols
    f32x4 acc[2][4] = {};
    const unsigned short* Aps[3] = {Ah, Ah, Al};
    const unsigned short* Bps[3] = {Bwh, Bwl, Bwh};

    for (int combo = 0; combo < 3; ++combo) {
        const unsigned short* __restrict__ Ap = Aps[combo];
        const unsigned short* __restrict__ Bp = Bps[combo];
        for (int k0 = 0; k0 < K; k0 += BK) {
            __syncthreads();  // previous-iter LDS reads done before DMA overwrite
            #pragma unroll
            for (int r = 0; r < 2; ++r) {
                int s = r * 256 + tid, row = s >> 3, c8 = s & 7;
                gload16(Ap + (size_t)(m0 + row) * K + k0 + c8 * 8, At + s * 8);
            }
            #pragma unroll
            for (int r = 0; r < 4; ++r) {
                int s = r * 256 + tid, row = s >> 3, c8 = s & 7;
                gload16(Bp + (size_t)(n0 + row) * K + k0 + c8 * 8, Bt + s * 8);
            }
            __syncthreads();  // drains vmcnt -> tiles ready
            #pragma unroll
            for (int kk = 0; kk < BK; kk += 32) {
                s16x8 a[2], bb[4];
                #pragma unroll
                for (int fm = 0; fm < 2; ++fm)
                    a[fm] = *(const s16x8*)(At + (wm * 32 + fm * 16 + (lane & 15)) * BK + kk + (lane >> 4) * 8);
                #pragma unroll
                for (int fn = 0; fn < 4; ++fn)
                    bb[fn] = *(const s16x8*)(Bt + (wn * 64 + fn * 16 + (lane & 15)) * BK + kk + (lane >> 4) * 8);
                #pragma unroll
                for (int fm = 0; fm < 2; ++fm)
                    #pragma unroll
                    for (int fn = 0; fn < 4; ++fn)
                        acc[fm][fn] = __builtin_amdgcn_mfma_f32_16x16x32_bf16(a[fm], bb[fn], acc[fm][fn], 0, 0, 0);
            }
        }
    }
    #pragma unroll
    for (int fm = 0; fm < 2; ++fm)
        #pragma unroll
        for (int fn = 0; fn < 4; ++fn)
            #pragma unroll
            for (int r = 0; r < 4; ++r) {
                int row  = m0 + wm * 32 + fm * 16 + (lane >> 4) * 4 + r;
                int coln = n0 + wn * 64 + fn * 16 + (lane & 15);
                float v = acc[fm][fn][r];
                if (bias) v += bias[coln];
                C[(size_t)row * Nn + coln] = v;
            }
}

// ---------------- rearrange qkv -> q'=[qh|ql], k'=[kh|kl] bf16 [B,H,N,128] ----------------
__global__ void k_rearrange(const float* __restrict__ qkv, unsigned short* __restrict__ qp,
                            unsigned short* __restrict__ kp) {
    int t = blockIdx.x * 256 + threadIdx.x;
    int d = t & 63, n = (t >> 6) & 1023, h = (t >> 16) & 7, b = t >> 19;
    const float* src = qkv + ((size_t)(b * N_ + n)) * (3 * D_) + h * HD_ + d;
    float q = src[0], k = src[D_];
    unsigned short qh = f2bf(q), ql = f2bf(q - bf2f(qh));
    unsigned short kh = f2bf(k), kl = f2bf(k - bf2f(kh));
    size_t base = ((size_t)(b * H_ + h) * N_ + n) * 128;
    qp[base + d] = qh; qp[base + 64 + d] = ql;
    kp[base + d] = kh; kp[base + 64 + d] = kl;
}

// ---------------- v -> vT bf16 [B,H,HD,N] (LDS transpose) ----------------
__global__ void k_vtrans(const float* __restrict__ qkv, unsigned short* __restrict__ vT) {
    __shared__ unsigned short T[64][65];
    int n0 = blockIdx.x * 64, h = blockIdx.y, b = blockIdx.z;
    int tid = threadIdx.x;
    #pragma unroll
    for (int rep = 0; rep < 16; ++rep) {
        int idx = rep * 256 + tid;
        int nl = idx >> 6, d = idx & 63;
        T[nl][d] = f2bf(qkv[((size_t)(b * N_ + n0 + nl)) * (3 * D_) + 2 * D_ + h * HD_ + d]);
    }
    __syncthreads();
    #pragma unroll
    for (int rep = 0; rep < 16; ++rep) {
        int idx = rep * 256 + tid;
        int dl = idx >> 6, nl = idx & 63;
        vT[((size_t)(b * H_ + h) * HD_ + dl) * N_ + n0 + nl] = T[nl][dl];
    }
}

// ---------------- per-node projection table: P'[c][bn] = f16(32 * W1[c][0..2] . coords[bn]) ----------------
__global__ void k_nodeproj(const float* __restrict__ coords, const float* __restrict__ W1,
                           unsigned short* __restrict__ Pt) {
    int t = blockIdx.x * 256 + threadIdx.x;          // 32 * 4096
    int bn = t & 4095, c = t >> 12;
    const float* cc = coords + (size_t)bn * 3;
    float v = 32.f * (W1[c * 4] * cc[0] + W1[c * 4 + 1] * cc[1] + W1[c * 4 + 2] * cc[2]);
    __half hv = __float2half(v);
    Pt[t] = *(unsigned short*)&hv;
}

// ---------------- pairwise MLP bias -> f16 [B,H,N,N] ----------------
// LUT gelu + f16 P' table (LDS) + fdot2 layer-2. alpha & valid-mask folded.
__global__ __launch_bounds__(256) void k_bias(
    const float* __restrict__ coords, const float* __restrict__ alpha,
    const float* __restrict__ W1, const float* __restrict__ b1,
    const float* __restrict__ W2, const float* __restrict__ b2,
    const unsigned short* __restrict__ Pt,   // f16 [32][B_*N_], prescaled x32
    unsigned short* __restrict__ biasH)
{
    __shared__ unsigned short sPj[32 * 256];   // 16 KB f16 (x32 prescale)
    __shared__ float lut[512];                 // 256 x (val, slope)
    __shared__ float SPi[32], swd32[32], sb2f[8];
    __shared__ unsigned short sW2h[8 * 32];    // f16 [h][32ch]
    const int tid = threadIdx.x;
    const int bid = blockIdx.x;
    const int j0 = (bid & 3) * 256;
    const int i  = (bid >> 2) & 1023;
    const int b  = bid >> 12;

    // LUT build: x_k = (k-128)/32
    {
        float xk = (tid - 128) * 0.03125f;
        float g0 = fast_gelu(xk);
        float g1 = fast_gelu(xk + 0.03125f);
        lut[tid * 2]     = g0;
        lut[tid * 2 + 1] = g1 - g0;
    }
    if (tid < 32) {
        const float* ci = coords + ((size_t)b * N_ + i) * 3;
        float w0 = W1[tid * 4], w1 = W1[tid * 4 + 1], w2 = W1[tid * 4 + 2], w3 = W1[tid * 4 + 3];
        SPi[tid]   = 32.f * (w0 * ci[0] + w1 * ci[1] + w2 * ci[2] + b1[tid]) + 128.f;
        swd32[tid] = 32.f * w3;
    }
    if (tid < 8) sb2f[tid] = b2[tid];
    {   // W2 -> f16
        __half hv = __float2half(W2[tid]);     // [8][32] row-major = 256 elems
        sW2h[tid] = *(unsigned short*)&hv;
    }
    {   // stage P' slice [32][j0..j0+255]
        #pragma unroll
        for (int p = 0; p < 4; ++p) {
            int idx = p * 256 + tid;
            int row = idx >> 5, off = (idx & 31) * 8;
            *(s16x8*)(sPj + row * 256 + off) =
                *(const s16x8*)(Pt + (size_t)row * (B_ * N_) + b * N_ + j0 + off);
        }
    }
    __syncthreads();

    const int j = j0 + tid;
    const float* ci = coords + ((size_t)b * N_ + i) * 3;
    const float* cj = coords + ((size_t)b * N_ + j) * 3;
    float dx = ci[0] - cj[0], dy = ci[1] - cj[1], dz = ci[2] - cj[2];
    float dist = sqrtf(dx * dx + dy * dy + dz * dz);

    float acc[8];
    #pragma unroll
    for (int h = 0; h < 8; ++h) acc[h] = 0.f;

    #pragma unroll 1
    for (int g = 0; g < 4; ++g) {              // 4 groups x 8 channels; runtime loop
        f16x2 gh[4];
        float gprev = 0.f;
        #pragma unroll
        for (int cc = 0; cc < 8; ++cc) {
            int c = g * 8 + cc;
            unsigned short u = sPj[c * 256 + tid];
            float pj = __half2float(*(const __half*)&u);
            float t  = fmaf(swd32[c], dist, SPi[c] - pj);   // table coordinate
            float tc = fminf(fmaxf(t, 0.f), 255.f);
            float fi = floorf(tc);
            int   ii = (int)fi;
            float fr = tc - fi;
            f32x2 vs = *(const f32x2*)(lut + ii * 2);
            float gg = fmaf(fr, vs[1], vs[0]);
            float xb = fmaf(t, 0.03125f, -4.f);             // x, for overflow
            gg = (t > 254.f) ? xb : gg;
            if (cc & 1) gh[cc >> 1] = __builtin_amdgcn_cvt_pkrtz(gprev, gg);
            else        gprev = gg;
        }
        #pragma unroll
        for (int h = 0; h < 8; ++h) {
            const f16x2* wp = (const f16x2*)(sW2h + h * 32 + g * 8);
            acc[h] = __builtin_amdgcn_fdot2(gh[0], wp[0], acc[h], false);
            acc[h] = __builtin_amdgcn_fdot2(gh[1], wp[1], acc[h], false);
            acc[h] = __builtin_amdgcn_fdot2(gh[2], wp[2], acc[h], false);
            acc[h] = __builtin_amdgcn_fdot2(gh[3], wp[3], acc[h], false);
        }
    }

    float vfac = (i >= 1 && j >= 1) ? alpha[0] : 0.f;   // NS=1 zeroing + alpha fold
    #pragma unroll
    for (int h = 0; h < 8; ++h) {
        __half hv = __float2half(vfac * (acc[h] + sb2f[h]));
        biasH[(((size_t)(b * H_ + h)) * N_ + i) * N_ + j] = *(unsigned short*)&hv;
    }
}

// ---------------- fused attention: DMA-staged K dots + register logits ----------------
// Split-accumulator MFMA (dots: 2 chains of 3; PV: 4 chains of 8) to cut serial
// MFMA-chain latency — the binding constraint at low occupancy.
__global__ __launch_bounds__(256, 4) void k_attn(
    const unsigned short* __restrict__ qp, const unsigned short* __restrict__ kp,
    const unsigned short* __restrict__ vT,
    const unsigned short* __restrict__ biasH,   // f16 [B,H,N,N]
    float* __restrict__ attnout,                // f32 [B,H,N,N] (pure output)
    const unsigned char* __restrict__ mraw, const int* __restrict__ flag,
    unsigned short* __restrict__ avh, unsigned short* __restrict__ avl)  // [B,N,D] hi/lo
{
    __shared__ s16x8 pool16[2048];            // 32 KB: K dbuf -> bias tile -> P
    __shared__ unsigned char smask[N_];
    __shared__ float redm[16][4];
    __shared__ float reds[16][4];
    const int tid = threadIdx.x, lane = tid & 63, wid = tid >> 6;

    // XCD-aware swizzle (bijective: 2048 % 8 == 0)
    int flat = blockIdx.x + 64 * (blockIdx.y + 8 * blockIdx.z);
    int swz  = (flat & 7) * 256 + (flat >> 3);
    const int i0 = (swz & 63) * 16;
    const int h  = (swz >> 6) & 7;
    const int b  = swz >> 9;
    const size_t bh = (size_t)(b * H_ + h);
    const int g = lane >> 4;                  // quad group 0..3
    const int cl = lane & 15;                 // col-lane

    if (flag[0] != 0) {
        for (int i2 = tid; i2 < N_; i2 += 256) smask[i2] = mraw[b * N_ + i2];
    } else {
        const int* mi = (const int*)mraw;
        for (int i2 = tid; i2 < N_; i2 += 256) smask[i2] = (unsigned char)(mi[b * N_ + i2] != 0);
    }

    // q fragments: rows i0+cl, layout [qh(64)|ql(64)]
    const unsigned short* qrow = qp + (bh * N_ + i0 + cl) * 128 + g * 8;
    s16x8 aqh0 = *(const s16x8*)(qrow);
    s16x8 aqh1 = *(const s16x8*)(qrow + 32);
    s16x8 aql0 = *(const s16x8*)(qrow + 64);
    s16x8 aql1 = *(const s16x8*)(qrow + 96);

    // staging source offsets (chunk-relative, XOR-swizzled source; LDS dest linear)
    int soff[4];
    #pragma unroll
    for (int p = 0; p < 4; ++p) {
        int o = p * 4096 + tid * 16;
        int row = o >> 8, offl = o & 255;
        soff[p] = row * 128 + ((offl ^ ((row & 7) << 4)) >> 1);
    }
    const unsigned short* kbase = kp + bh * (size_t)N_ * 128;

    const int lr = wid * 16 + cl;
    int rdoff[4];
    #pragma unroll
    for (int f = 0; f < 4; ++f)
        rdoff[f] = lr * 256 + ((g * 16 + f * 64) ^ ((lr & 7) << 4));

    char* poolb = (char*)pool16;

    // stage chunk 0 via DMA
    #pragma unroll
    for (int p = 0; p < 4; ++p)
        gload16(kbase + soff[p], poolb + p * 4096 + tid * 16);
    __syncthreads();

    // pipelined chunk loop: issue DMA for c+1 -> compute c (2 indep chains) -> barrier
    f32x4 acc[16];
    #pragma unroll
    for (int c = 0; c < 16; ++c) {
        if (c < 15) {
            const unsigned short* cb = kbase + (size_t)(c + 1) * 8192;
            char* wb = poolb + ((c + 1) & 1) * 16384;
            #pragma unroll
            for (int p = 0; p < 4; ++p)
                gload16(cb + soff[p], wb + p * 4096 + tid * 16);
        }
        char* kb = poolb + (c & 1) * 16384;
        s16x8 k0 = *(const s16x8*)(kb + rdoff[0]);
        s16x8 k1 = *(const s16x8*)(kb + rdoff[1]);
        s16x8 k2 = *(const s16x8*)(kb + rdoff[2]);
        s16x8 k3 = *(const s16x8*)(kb + rdoff[3]);
        f32x4 a0 = {0.f, 0.f, 0.f, 0.f};
        f32x4 a1 = {0.f, 0.f, 0.f, 0.f};
        a0 = __builtin_amdgcn_mfma_f32_16x16x32_bf16(aqh0, k0, a0, 0, 0, 0);
        a1 = __builtin_amdgcn_mfma_f32_16x16x32_bf16(aqh1, k1, a1, 0, 0, 0);
        a0 = __builtin_amdgcn_mfma_f32_16x16x32_bf16(aqh0, k2, a0, 0, 0, 0);
        a1 = __builtin_amdgcn_mfma_f32_16x16x32_bf16(aqh1, k3, a1, 0, 0, 0);
        a0 = __builtin_amdgcn_mfma_f32_16x16x32_bf16(aql0, k0, a0, 0, 0, 0);
        a1 = __builtin_amdgcn_mfma_f32_16x16x32_bf16(aql1, k1, a1, 0, 0, 0);
        acc[c] = a0 + a1;
        __syncthreads();
    }

    // bias tile: DMA copy 32 KB global f16 -> pool (K data dead)
    {
        const unsigned short* bsrc = biasH + (bh * N_ + i0) * N_;
        unsigned short* bl = (unsigned short*)poolb;
        #pragma unroll
        for (int p2 = 0; p2 < 8; ++p2) {
            int idx = p2 * 256 + tid;
            gload16(bsrc + (size_t)idx * 8, bl + idx * 8);
        }
    }
    __syncthreads();

    // logits: scale + bias + mask (col = (j*4+wid)*16 + cl)
    const float scale = 0.125f;               // HD^-0.5
    const unsigned short* bl = (const unsigned short*)poolb;
    #pragma unroll
    for (int j = 0; j < 16; ++j) {
        const int col = (j * 4 + wid) * 16 + cl;
        const bool mj = (smask[col] != 0);
        #pragma unroll
        for (int r = 0; r < 4; ++r) {
            unsigned short u = bl[(g * 4 + r) * 1024 + col];
            float bv = __half2float(*(const __half*)&u);
            acc[j][r] = mj ? -1e30f : fmaf(acc[j][r], scale, bv);
        }
    }

    // row max
    float m[4];
    #pragma unroll
    for (int r = 0; r < 4; ++r) {
        float mm = acc[0][r];
        #pragma unroll
        for (int j = 1; j < 16; ++j) mm = fmaxf(mm, acc[j][r]);
        m[r] = mm;
    }
    #pragma unroll
    for (int msk = 1; msk < 16; msk <<= 1)
        #pragma unroll
        for (int r = 0; r < 4; ++r) m[r] = fmaxf(m[r], __shfl_xor(m[r], msk));
    if (cl == 0)
        #pragma unroll
        for (int r = 0; r < 4; ++r) redm[g * 4 + r][wid] = m[r];
    __syncthreads();
    #pragma unroll
    for (int r = 0; r < 4; ++r) {
        int row = g * 4 + r;
        m[r] = fmaxf(fmaxf(redm[row][0], redm[row][1]), fmaxf(redm[row][2], redm[row][3]));
    }

    // exp + row sum
    float s[4] = {0.f, 0.f, 0.f, 0.f};
    #pragma unroll
    for (int j = 0; j < 16; ++j)
        #pragma unroll
        for (int r = 0; r < 4; ++r) {
            float e = __expf(acc[j][r] - m[r]);
            acc[j][r] = e;
            s[r] += e;
        }
    #pragma unroll
    for (int msk = 1; msk < 16; msk <<= 1)
        #pragma unroll
        for (int r = 0; r < 4; ++r) s[r] += __shfl_xor(s[r], msk);
    if (cl == 0)
        #pragma unroll
        for (int r = 0; r < 4; ++r) reds[g * 4 + r][wid] = s[r];
    __syncthreads();
    float sinv[4];
    #pragma unroll
    for (int r = 0; r < 4; ++r) {
        int row = g * 4 + r;
        sinv[r] = 1.0f / (reds[row][0] + reds[row][1] + reds[row][2] + reds[row][3]);
    }

    // attn write (nontemporal) + P write (swizzled bf16; bias dead)
    float* gattn = attnout + (bh * N_ + i0) * N_;
    char* Pb = poolb;
    #pragma unroll
    for (int j = 0; j < 16; ++j) {
        const int col = (j * 4 + wid) * 16 + cl;
        #pragma unroll
        for (int r = 0; r < 4; ++r) {
            const int row = g * 4 + r;
            float e = acc[j][r];
            __builtin_nontemporal_store(e * sinv[r], &gattn[(size_t)row * N_ + col]);
            int byte = row * 2048 + ((col * 2) ^ ((row & 7) << 4));
            *(unsigned short*)(Pb + byte) = f2bf(e);
        }
    }
    __syncthreads();

    // PV: 4 independent accumulator chains (8 MFMA each), tree-summed
    {
        const int d0 = wid * 16;
        f32x4 p0 = {0.f, 0.f, 0.f, 0.f};
        f32x4 p1 = {0.f, 0.f, 0.f, 0.f};
        f32x4 p2 = {0.f, 0.f, 0.f, 0.f};
        f32x4 p3 = {0.f, 0.f, 0.f, 0.f};
        const unsigned short* vrow = vT + (bh * HD_ + d0 + cl) * N_ + g * 8;
        const int rowA = cl;
        const int swzb = (rowA & 7) << 4;
        #pragma unroll
        for (int kk = 0; kk < N_; kk += 128) {
            s16x8 b0 = *(const s16x8*)(vrow + kk);
            s16x8 b1 = *(const s16x8*)(vrow + kk + 32);
            s16x8 b2 = *(const s16x8*)(vrow + kk + 64);
            s16x8 b3 = *(const s16x8*)(vrow + kk + 96);
            s16x8 af0 = *(const s16x8*)(Pb + rowA * 2048 + (((kk      + g * 8) * 2) ^ swzb));
            s16x8 af1 = *(const s16x8*)(Pb + rowA * 2048 + (((kk + 32 + g * 8) * 2) ^ swzb));
            s16x8 af2 = *(const s16x8*)(Pb + rowA * 2048 + (((kk + 64 + g * 8) * 2) ^ swzb));
            s16x8 af3 = *(const s16x8*)(Pb + rowA * 2048 + (((kk + 96 + g * 8) * 2) ^ swzb));
            p0 = __builtin_amdgcn_mfma_f32_16x16x32_bf16(af0, b0, p0, 0, 0, 0);
            p1 = __builtin_amdgcn_mfma_f32_16x16x32_bf16(af1, b1, p1, 0, 0, 0);
            p2 = __builtin_amdgcn_mfma_f32_16x16x32_bf16(af2, b2, p2, 0, 0, 0);
            p3 = __builtin_amdgcn_mfma_f32_16x16x32_bf16(af3, b3, p3, 0, 0, 0);
        }
        f32x4 acc2 = (p0 + p1) + (p2 + p3);
        #pragma unroll
        for (int r = 0; r < 4; ++r) {
            const int row = g * 4 + r;
            const int dd = d0 + cl;
            float v = acc2[r] * sinv[r];
            unsigned short hv = f2bf(v);
            size_t o = ((size_t)(b * N_) + i0 + row) * D_ + h * HD_ + dd;
            avh[o] = hv;
            avl[o] = f2bf(v - bf2f(hv));
        }
    }
}

extern "C" void kernel_launch(void* const* d_in, const int* in_sizes, int n_in,
                              void* d_out, int out_size, void* d_ws, size_t ws_size,
                              hipStream_t stream) {
    (void)in_sizes; (void)n_in; (void)out_size; (void)ws_size;
    const float* x      = (const float*)d_in[0];
    const float* coords = (const float*)d_in[1];
    const unsigned char* kpm = (const unsigned char*)d_in[2];
    const float* alpha  = (const float*)d_in[3];
    const float* W1     = (const float*)d_in[4];
    const float* b1     = (const float*)d_in[5];
    const float* W2     = (const float*)d_in[6];
    const float* b2     = (const float*)d_in[7];
    const float* Wqkv   = (const float*)d_in[8];
    const float* Wout   = (const float*)d_in[9];
    const float* bout   = (const float*)d_in[10];

    float* out  = (float*)d_out;                     // [B,N,D]
    float* attn = out + (size_t)B_ * N_ * D_;        // [B,H,N,N] (pure output)

    char* w = (char*)d_ws;
    auto alloc = [&](size_t bytes) { char* p = w; w += (bytes + 255) & ~(size_t)255; return p; };
    const size_t SZ_X  = (size_t)B_ * N_ * D_;
    const size_t SZ_WQ = (size_t)3 * D_ * D_;
    const size_t SZ_WO = (size_t)D_ * D_;

    // long-lived
    unsigned short* wo_hi = (unsigned short*)alloc(SZ_WO * 2);
    unsigned short* wo_lo = (unsigned short*)alloc(SZ_WO * 2);
    unsigned short* qp = (unsigned short*)alloc((size_t)B_ * H_ * N_ * 128 * 2);
    unsigned short* kp = (unsigned short*)alloc((size_t)B_ * H_ * N_ * 128 * 2);
    unsigned short* vT = (unsigned short*)alloc((size_t)B_ * H_ * HD_ * N_ * 2);
    unsigned short* av_hi = (unsigned short*)alloc(SZ_X * 2);
    unsigned short* av_lo = (unsigned short*)alloc(SZ_X * 2);
    unsigned short* Pt = (unsigned short*)alloc((size_t)32 * B_ * N_ * 2);   // 256 KB
    int* flag = (int*)alloc(256);

    // union region: stage-1 (x/wq staging + qkv) vs stage-2 (f16 bias)
    char* uni = (char*)alloc(0);
    unsigned short* x_hi = (unsigned short*)uni;
    unsigned short* x_lo = x_hi + SZ_X;
    unsigned short* wq_hi = x_lo + SZ_X;
    unsigned short* wq_lo = wq_hi + SZ_WQ;
    float* qkv = (float*)(wq_lo + SZ_WQ);
    unsigned short* biasH = (unsigned short*)uni;     // 67 MB, aliases stage-1

    k_split<<<(int)((SZ_X + 255) / 256), 256, 0, stream>>>(x, x_hi, x_lo, (int)SZ_X);
    k_split<<<(int)((SZ_WQ + 255) / 256), 256, 0, stream>>>(Wqkv, wq_hi, wq_lo, (int)SZ_WQ);
    k_split<<<(int)((SZ_WO + 255) / 256), 256, 0, stream>>>(Wout, wo_hi, wo_lo, (int)SZ_WO);
    k_mask_detect<<<1, 256, 0, stream>>>(kpm, flag);
    k_nodeproj<<<(32 * B_ * N_) / 256, 256, 0, stream>>>(coords, W1, Pt);
    k_gemm3<<<dim3(64, 12), 256, 0, stream>>>(x_hi, x_lo, wq_hi, wq_lo, qkv, nullptr,
                                              B_ * N_, 3 * D_, D_);
    k_rearrange<<<(B_ * H_ * N_ * HD_) / 256, 256, 0, stream>>>(qkv, qp, kp);
    k_vtrans<<<dim3(16, H_, B_), 256, 0, stream>>>(qkv, vT);
    k_bias<<<(B_ * N_ * N_) / 256, 256, 0, stream>>>(coords, alpha, W1, b1, W2, b2, Pt, biasH);
    k_attn<<<dim3(64, H_, B_), 256, 0, stream>>>(qp, kp, vT, biasH, attn, kpm, flag, av_hi, av_lo);
    k_gemm3<<<dim3(64, 4), 256, 0, stream>>>(av_hi, av_lo, wo_hi, wo_lo, out, bout,
                                             B_ * N_, D_, D_);
}

// Round 19
// 236.896 us; speedup vs baseline: 1.1199x; 1.1199x over previous
//
#include <hip/hip_runtime.h>
#include <hip/hip_fp16.h>
#include <stdint.h>
#include <math.h>

#define B_  4
#define N_  1024
#define D_  512
#define H_  8
#define HD_ 64

typedef short s16x8 __attribute__((ext_vector_type(8)));
typedef float f32x4 __attribute__((ext_vector_type(4)));
typedef float f32x2 __attribute__((ext_vector_type(2)));
typedef __fp16 f16x2 __attribute__((ext_vector_type(2)));   // matches cvt_pkrtz / fdot2

typedef const __attribute__((address_space(1))) void* gas1p;
typedef __attribute__((address_space(3))) void* las3p;
__device__ __forceinline__ void gload16(const void* g, void* l) {
    __builtin_amdgcn_global_load_lds((gas1p)g, (las3p)l, 16, 0, 0);
}

__device__ __forceinline__ unsigned short f2bf(float f) {
    unsigned u = __float_as_uint(f);
    u += 0x7fffu + ((u >> 16) & 1u);      // RNE
    return (unsigned short)(u >> 16);
}
__device__ __forceinline__ float bf2f(unsigned short h) {
    return __uint_as_float(((unsigned)h) << 16);
}

// fast exact-erf gelu: A&S 7.1.26 rational, |erf err| <= 1.5e-7, branch-free
__device__ __forceinline__ float fast_gelu(float x) {
    float ax = fabsf(x) * 0.7071067811865476f;          // |x|/sqrt(2)
    float t  = __builtin_amdgcn_rcpf(fmaf(0.3275911f, ax, 1.0f));
    float e  = __expf(-ax * ax);
    float poly = t * fmaf(t, fmaf(t, fmaf(t, fmaf(t, 1.061405429f, -1.453152027f),
                                          1.421413741f), -0.284496736f), 0.254829592f);
    float erfv = 1.0f - poly * e;                        // erf(|x|/sqrt2)
    float s = copysignf(erfv, x);
    return 0.5f * x * (1.0f + s);
}

// ---------------- split f32 -> (hi, lo) bf16 ----------------
__global__ void k_split(const float* __restrict__ s, unsigned short* __restrict__ h,
                        unsigned short* __restrict__ l, int n) {
    int i = blockIdx.x * 256 + threadIdx.x;
    if (i < n) {
        float x = s[i];
        unsigned short hb = f2bf(x);
        h[i] = hb;
        l[i] = f2bf(x - bf2f(hb));
    }
}

// ---------------- mask layout detection ----------------
__global__ void k_mask_detect(const unsigned char* __restrict__ m, int* __restrict__ flag) {
    __shared__ int s;
    if (threadIdx.x == 0) s = 0;
    __syncthreads();
    int found = 0;
    for (int i = threadIdx.x; i < B_ * N_; i += 256)
        if ((i & 3) && m[i]) found = 1;
    if (found) atomicOr(&s, 1);
    __syncthreads();
    if (threadIdx.x == 0) flag[0] = s;
}

// ---------------- split-bf16 GEMM: C[M,N] = A[M,K] @ B[N,K]^T (+bias) ----------------
// Staging via global_load_lds (16B DMA): no reg round-trip, no address VALU.
__global__ __launch_bounds__(256) void k_gemm3(
    const unsigned short* __restrict__ Ah, const unsigned short* __restrict__ Al,
    const unsigned short* __restrict__ Bwh, const unsigned short* __restrict__ Bwl,
    float* __restrict__ C, const float* __restrict__ bias, int M, int Nn, int K)
{
    constexpr int BM = 64, BN = 128, BK = 64;
    __shared__ unsigned short At[BM * BK];
    __shared__ unsigned short Bt[BN * BK];
    const int tid = threadIdx.x, lane = tid & 63, wid = tid >> 6;
    const int m0 = blockIdx.x * BM, n0 = blockIdx.y * BN;
    const int wm = wid >> 1, wn = wid & 1;   // wave tile: 32 rows x 64 cols
    f32x4 acc[2][4] = {};
    const unsigned short* Aps[3] = {Ah, Ah, Al};
    const unsigned short* Bps[3] = {Bwh, Bwl, Bwh};

    for (int combo = 0; combo < 3; ++combo) {
        const unsigned short* __restrict__ Ap = Aps[combo];
        const unsigned short* __restrict__ Bp = Bps[combo];
        for (int k0 = 0; k0 < K; k0 += BK) {
            __syncthreads();  // previous-iter LDS reads done before DMA overwrite
            #pragma unroll
            for (int r = 0; r < 2; ++r) {
                int s = r * 256 + tid, row = s >> 3, c8 = s & 7;
                gload16(Ap + (size_t)(m0 + row) * K + k0 + c8 * 8, At + s * 8);
            }
            #pragma unroll
            for (int r = 0; r < 4; ++r) {
                int s = r * 256 + tid, row = s >> 3, c8 = s & 7;
                gload16(Bp + (size_t)(n0 + row) * K + k0 + c8 * 8, Bt + s * 8);
            }
            __syncthreads();  // drains vmcnt -> tiles ready
            #pragma unroll
            for (int kk = 0; kk < BK; kk += 32) {
                s16x8 a[2], bb[4];
                #pragma unroll
                for (int fm = 0; fm < 2; ++fm)
                    a[fm] = *(const s16x8*)(At + (wm * 32 + fm * 16 + (lane & 15)) * BK + kk + (lane >> 4) * 8);
                #pragma unroll
                for (int fn = 0; fn < 4; ++fn)
                    bb[fn] = *(const s16x8*)(Bt + (wn * 64 + fn * 16 + (lane & 15)) * BK + kk + (lane >> 4) * 8);
                #pragma unroll
                for (int fm = 0; fm < 2; ++fm)
                    #pragma unroll
                    for (int fn = 0; fn < 4; ++fn)
                        acc[fm][fn] = __builtin_amdgcn_mfma_f32_16x16x32_bf16(a[fm], bb[fn], acc[fm][fn], 0, 0, 0);
            }
        }
    }
    #pragma unroll
    for (int fm = 0; fm < 2; ++fm)
        #pragma unroll
        for (int fn = 0; fn < 4; ++fn)
            #pragma unroll
            for (int r = 0; r < 4; ++r) {
                int row  = m0 + wm * 32 + fm * 16 + (lane >> 4) * 4 + r;
                int coln = n0 + wn * 64 + fn * 16 + (lane & 15);
                float v = acc[fm][fn][r];
                if (bias) v += bias[coln];
                C[(size_t)row * Nn + coln] = v;
            }
}

// ---------------- rearrange qkv -> q'=[qh|ql], k'=[kh|kl] bf16 [B,H,N,128] ----------------
__global__ void k_rearrange(const float* __restrict__ qkv, unsigned short* __restrict__ qp,
                            unsigned short* __restrict__ kp) {
    int t = blockIdx.x * 256 + threadIdx.x;
    int d = t & 63, n = (t >> 6) & 1023, h = (t >> 16) & 7, b = t >> 19;
    const float* src = qkv + ((size_t)(b * N_ + n)) * (3 * D_) + h * HD_ + d;
    float q = src[0], k = src[D_];
    unsigned short qh = f2bf(q), ql = f2bf(q - bf2f(qh));
    unsigned short kh = f2bf(k), kl = f2bf(k - bf2f(kh));
    size_t base = ((size_t)(b * H_ + h) * N_ + n) * 128;
    qp[base + d] = qh; qp[base + 64 + d] = ql;
    kp[base + d] = kh; kp[base + 64 + d] = kl;
}

// ---------------- v -> vT bf16 [B,H,HD,N] (LDS transpose) ----------------
__global__ void k_vtrans(const float* __restrict__ qkv, unsigned short* __restrict__ vT) {
    __shared__ unsigned short T[64][65];
    int n0 = blockIdx.x * 64, h = blockIdx.y, b = blockIdx.z;
    int tid = threadIdx.x;
    #pragma unroll
    for (int rep = 0; rep < 16; ++rep) {
        int idx = rep * 256 + tid;
        int nl = idx >> 6, d = idx & 63;
        T[nl][d] = f2bf(qkv[((size_t)(b * N_ + n0 + nl)) * (3 * D_) + 2 * D_ + h * HD_ + d]);
    }
    __syncthreads();
    #pragma unroll
    for (int rep = 0; rep < 16; ++rep) {
        int idx = rep * 256 + tid;
        int dl = idx >> 6, nl = idx & 63;
        vT[((size_t)(b * H_ + h) * HD_ + dl) * N_ + n0 + nl] = T[nl][dl];
    }
}

// ---------------- per-node projection table: P'[c][bn] = f16(32 * W1[c][0..2] . coords[bn]) ----------------
__global__ void k_nodeproj(const float* __restrict__ coords, const float* __restrict__ W1,
                           unsigned short* __restrict__ Pt) {
    int t = blockIdx.x * 256 + threadIdx.x;          // 32 * 4096
    int bn = t & 4095, c = t >> 12;
    const float* cc = coords + (size_t)bn * 3;
    float v = 32.f * (W1[c * 4] * cc[0] + W1[c * 4 + 1] * cc[1] + W1[c * 4 + 2] * cc[2]);
    __half hv = __float2half(v);
    Pt[t] = *(unsigned short*)&hv;
}

// ---------------- pairwise MLP bias -> f16 [B,H,N,N] ----------------
// LUT gelu + f16 P' table (LDS) + fdot2 layer-2. alpha & valid-mask folded.
__global__ __launch_bounds__(256) void k_bias(
    const float* __restrict__ coords, const float* __restrict__ alpha,
    const float* __restrict__ W1, const float* __restrict__ b1,
    const float* __restrict__ W2, const float* __restrict__ b2,
    const unsigned short* __restrict__ Pt,   // f16 [32][B_*N_], prescaled x32
    unsigned short* __restrict__ biasH)
{
    __shared__ unsigned short sPj[32 * 256];   // 16 KB f16 (x32 prescale)
    __shared__ float lut[512];                 // 256 x (val, slope)
    __shared__ float SPi[32], swd32[32], sb2f[8];
    __shared__ unsigned short sW2h[8 * 32];    // f16 [h][32ch]
    const int tid = threadIdx.x;
    const int bid = blockIdx.x;
    const int j0 = (bid & 3) * 256;
    const int i  = (bid >> 2) & 1023;
    const int b  = bid >> 12;

    // LUT build: x_k = (k-128)/32
    {
        float xk = (tid - 128) * 0.03125f;
        float g0 = fast_gelu(xk);
        float g1 = fast_gelu(xk + 0.03125f);
        lut[tid * 2]     = g0;
        lut[tid * 2 + 1] = g1 - g0;
    }
    if (tid < 32) {
        const float* ci = coords + ((size_t)b * N_ + i) * 3;
        float w0 = W1[tid * 4], w1 = W1[tid * 4 + 1], w2 = W1[tid * 4 + 2], w3 = W1[tid * 4 + 3];
        SPi[tid]   = 32.f * (w0 * ci[0] + w1 * ci[1] + w2 * ci[2] + b1[tid]) + 128.f;
        swd32[tid] = 32.f * w3;
    }
    if (tid < 8) sb2f[tid] = b2[tid];
    {   // W2 -> f16
        __half hv = __float2half(W2[tid]);     // [8][32] row-major = 256 elems
        sW2h[tid] = *(unsigned short*)&hv;
    }
    {   // stage P' slice [32][j0..j0+255]
        #pragma unroll
        for (int p = 0; p < 4; ++p) {
            int idx = p * 256 + tid;
            int row = idx >> 5, off = (idx & 31) * 8;
            *(s16x8*)(sPj + row * 256 + off) =
                *(const s16x8*)(Pt + (size_t)row * (B_ * N_) + b * N_ + j0 + off);
        }
    }
    __syncthreads();

    const int j = j0 + tid;
    const float* ci = coords + ((size_t)b * N_ + i) * 3;
    const float* cj = coords + ((size_t)b * N_ + j) * 3;
    float dx = ci[0] - cj[0], dy = ci[1] - cj[1], dz = ci[2] - cj[2];
    float dist = sqrtf(dx * dx + dy * dy + dz * dz);

    float acc[8];
    #pragma unroll
    for (int h = 0; h < 8; ++h) acc[h] = 0.f;

    #pragma unroll 1
    for (int g = 0; g < 4; ++g) {              // 4 groups x 8 channels; runtime loop
        f16x2 gh[4];
        float gprev = 0.f;
        #pragma unroll
        for (int cc = 0; cc < 8; ++cc) {
            int c = g * 8 + cc;
            unsigned short u = sPj[c * 256 + tid];
            float pj = __half2float(*(const __half*)&u);
            float t  = fmaf(swd32[c], dist, SPi[c] - pj);   // table coordinate
            float tc = fminf(fmaxf(t, 0.f), 255.f);
            float fi = floorf(tc);
            int   ii = (int)fi;
            float fr = tc - fi;
            f32x2 vs = *(const f32x2*)(lut + ii * 2);
            float gg = fmaf(fr, vs[1], vs[0]);
            float xb = fmaf(t, 0.03125f, -4.f);             // x, for overflow
            gg = (t > 254.f) ? xb : gg;
            if (cc & 1) gh[cc >> 1] = __builtin_amdgcn_cvt_pkrtz(gprev, gg);
            else        gprev = gg;
        }
        #pragma unroll
        for (int h = 0; h < 8; ++h) {
            const f16x2* wp = (const f16x2*)(sW2h + h * 32 + g * 8);
            acc[h] = __builtin_amdgcn_fdot2(gh[0], wp[0], acc[h], false);
            acc[h] = __builtin_amdgcn_fdot2(gh[1], wp[1], acc[h], false);
            acc[h] = __builtin_amdgcn_fdot2(gh[2], wp[2], acc[h], false);
            acc[h] = __builtin_amdgcn_fdot2(gh[3], wp[3], acc[h], false);
        }
    }

    float vfac = (i >= 1 && j >= 1) ? alpha[0] : 0.f;   // NS=1 zeroing + alpha fold
    #pragma unroll
    for (int h = 0; h < 8; ++h) {
        __half hv = __float2half(vfac * (acc[h] + sb2f[h]));
        biasH[(((size_t)(b * H_ + h)) * N_ + i) * N_ + j] = *(unsigned short*)&hv;
    }
}

// ---------------- fused attention: DMA-staged K dots + register logits ----------------
// K-chunks + bias tile staged via global_load_lds (linear LDS dest, pre-swizzled
// global source). launch_bounds(256,4): 64V+64A -> 4 blocks/CU. NT attn stores.
__global__ __launch_bounds__(256, 4) void k_attn(
    const unsigned short* __restrict__ qp, const unsigned short* __restrict__ kp,
    const unsigned short* __restrict__ vT,
    const unsigned short* __restrict__ biasH,   // f16 [B,H,N,N]
    float* __restrict__ attnout,                // f32 [B,H,N,N] (pure output)
    const unsigned char* __restrict__ mraw, const int* __restrict__ flag,
    unsigned short* __restrict__ avh, unsigned short* __restrict__ avl)  // [B,N,D] hi/lo
{
    __shared__ s16x8 pool16[2048];            // 32 KB: K dbuf -> bias tile -> P
    __shared__ unsigned char smask[N_];
    __shared__ float redm[16][4];
    __shared__ float reds[16][4];
    const int tid = threadIdx.x, lane = tid & 63, wid = tid >> 6;

    // XCD-aware swizzle (bijective: 2048 % 8 == 0)
    int flat = blockIdx.x + 64 * (blockIdx.y + 8 * blockIdx.z);
    int swz  = (flat & 7) * 256 + (flat >> 3);
    const int i0 = (swz & 63) * 16;
    const int h  = (swz >> 6) & 7;
    const int b  = swz >> 9;
    const size_t bh = (size_t)(b * H_ + h);
    const int g = lane >> 4;                  // quad group 0..3
    const int cl = lane & 15;                 // col-lane

    if (flag[0] != 0) {
        for (int i2 = tid; i2 < N_; i2 += 256) smask[i2] = mraw[b * N_ + i2];
    } else {
        const int* mi = (const int*)mraw;
        for (int i2 = tid; i2 < N_; i2 += 256) smask[i2] = (unsigned char)(mi[b * N_ + i2] != 0);
    }

    // q fragments: rows i0+cl, layout [qh(64)|ql(64)]
    const unsigned short* qrow = qp + (bh * N_ + i0 + cl) * 128 + g * 8;
    s16x8 aqh0 = *(const s16x8*)(qrow);
    s16x8 aqh1 = *(const s16x8*)(qrow + 32);
    s16x8 aql0 = *(const s16x8*)(qrow + 64);
    s16x8 aql1 = *(const s16x8*)(qrow + 96);

    // staging source offsets (chunk-relative, XOR-swizzled source; LDS dest linear)
    int soff[4];
    #pragma unroll
    for (int p = 0; p < 4; ++p) {
        int o = p * 4096 + tid * 16;
        int row = o >> 8, offl = o & 255;
        soff[p] = row * 128 + ((offl ^ ((row & 7) << 4)) >> 1);
    }
    const unsigned short* kbase = kp + bh * (size_t)N_ * 128;

    const int lr = wid * 16 + cl;
    int rdoff[4];
    #pragma unroll
    for (int f = 0; f < 4; ++f)
        rdoff[f] = lr * 256 + ((g * 16 + f * 64) ^ ((lr & 7) << 4));

    char* poolb = (char*)pool16;

    // stage chunk 0 via DMA
    #pragma unroll
    for (int p = 0; p < 4; ++p)
        gload16(kbase + soff[p], poolb + p * 4096 + tid * 16);
    __syncthreads();

    // pipelined chunk loop: issue DMA for c+1 -> compute c -> barrier (drains vmcnt)
    f32x4 acc[16];
    #pragma unroll
    for (int c = 0; c < 16; ++c) {
        if (c < 15) {
            const unsigned short* cb = kbase + (size_t)(c + 1) * 8192;
            char* wb = poolb + ((c + 1) & 1) * 16384;
            #pragma unroll
            for (int p = 0; p < 4; ++p)
                gload16(cb + soff[p], wb + p * 4096 + tid * 16);
        }
        char* kb = poolb + (c & 1) * 16384;
        s16x8 k0 = *(const s16x8*)(kb + rdoff[0]);
        s16x8 k1 = *(const s16x8*)(kb + rdoff[1]);
        s16x8 k2 = *(const s16x8*)(kb + rdoff[2]);
        s16x8 k3 = *(const s16x8*)(kb + rdoff[3]);
        f32x4 a = {0.f, 0.f, 0.f, 0.f};
        a = __builtin_amdgcn_mfma_f32_16x16x32_bf16(aqh0, k0, a, 0, 0, 0);
        a = __builtin_amdgcn_mfma_f32_16x16x32_bf16(aqh1, k1, a, 0, 0, 0);
        a = __builtin_amdgcn_mfma_f32_16x16x32_bf16(aqh0, k2, a, 0, 0, 0);
        a = __builtin_amdgcn_mfma_f32_16x16x32_bf16(aqh1, k3, a, 0, 0, 0);
        a = __builtin_amdgcn_mfma_f32_16x16x32_bf16(aql0, k0, a, 0, 0, 0);
        a = __builtin_amdgcn_mfma_f32_16x16x32_bf16(aql1, k1, a, 0, 0, 0);
        acc[c] = a;
        __syncthreads();
    }

    // bias tile: DMA copy 32 KB global f16 -> pool (K data dead)
    {
        const unsigned short* bsrc = biasH + (bh * N_ + i0) * N_;
        unsigned short* bl = (unsigned short*)poolb;
        #pragma unroll
        for (int p2 = 0; p2 < 8; ++p2) {
            int idx = p2 * 256 + tid;
            gload16(bsrc + (size_t)idx * 8, bl + idx * 8);
        }
    }
    __syncthreads();

    // logits: scale + bias + mask (col = (j*4+wid)*16 + cl)
    const float scale = 0.125f;               // HD^-0.5
    const unsigned short* bl = (const unsigned short*)poolb;
    #pragma unroll
    for (int j = 0; j < 16; ++j) {
        const int col = (j * 4 + wid) * 16 + cl;
        const bool mj = (smask[col] != 0);
        #pragma unroll
        for (int r = 0; r < 4; ++r) {
            unsigned short u = bl[(g * 4 + r) * 1024 + col];
            float bv = __half2float(*(const __half*)&u);
            acc[j][r] = mj ? -1e30f : fmaf(acc[j][r], scale, bv);
        }
    }

    // row max
    float m[4];
    #pragma unroll
    for (int r = 0; r < 4; ++r) {
        float mm = acc[0][r];
        #pragma unroll
        for (int j = 1; j < 16; ++j) mm = fmaxf(mm, acc[j][r]);
        m[r] = mm;
    }
    #pragma unroll
    for (int msk = 1; msk < 16; msk <<= 1)
        #pragma unroll
        for (int r = 0; r < 4; ++r) m[r] = fmaxf(m[r], __shfl_xor(m[r], msk));
    if (cl == 0)
        #pragma unroll
        for (int r = 0; r < 4; ++r) redm[g * 4 + r][wid] = m[r];
    __syncthreads();
    #pragma unroll
    for (int r = 0; r < 4; ++r) {
        int row = g * 4 + r;
        m[r] = fmaxf(fmaxf(redm[row][0], redm[row][1]), fmaxf(redm[row][2], redm[row][3]));
    }

    // exp + row sum
    float s[4] = {0.f, 0.f, 0.f, 0.f};
    #pragma unroll
    for (int j = 0; j < 16; ++j)
        #pragma unroll
        for (int r = 0; r < 4; ++r) {
            float e = __expf(acc[j][r] - m[r]);
            acc[j][r] = e;
            s[r] += e;
        }
    #pragma unroll
    for (int msk = 1; msk < 16; msk <<= 1)
        #pragma unroll
        for (int r = 0; r < 4; ++r) s[r] += __shfl_xor(s[r], msk);
    if (cl == 0)
        #pragma unroll
        for (int r = 0; r < 4; ++r) reds[g * 4 + r][wid] = s[r];
    __syncthreads();
    float sinv[4];
    #pragma unroll
    for (int r = 0; r < 4; ++r) {
        int row = g * 4 + r;
        sinv[r] = 1.0f / (reds[row][0] + reds[row][1] + reds[row][2] + reds[row][3]);
    }

    // attn write (nontemporal) + P write (swizzled bf16; bias dead)
    float* gattn = attnout + (bh * N_ + i0) * N_;
    char* Pb = poolb;
    #pragma unroll
    for (int j = 0; j < 16; ++j) {
        const int col = (j * 4 + wid) * 16 + cl;
        #pragma unroll
        for (int r = 0; r < 4; ++r) {
            const int row = g * 4 + r;
            float e = acc[j][r];
            __builtin_nontemporal_store(e * sinv[r], &gattn[(size_t)row * N_ + col]);
            int byte = row * 2048 + ((col * 2) ^ ((row & 7) << 4));
            *(unsigned short*)(Pb + byte) = f2bf(e);
        }
    }
    __syncthreads();

    // PV
    {
        const int d0 = wid * 16;
        f32x4 acc2 = {0.f, 0.f, 0.f, 0.f};
        const unsigned short* vrow = vT + (bh * HD_ + d0 + cl) * N_ + g * 8;
        const int rowA = cl;
        const int swzb = (rowA & 7) << 4;
        for (int kk = 0; kk < N_; kk += 32) {
            s16x8 bfrag = *(const s16x8*)(vrow + kk);
            int byte = rowA * 2048 + (((kk + g * 8) * 2) ^ swzb);
            s16x8 af = *(const s16x8*)(Pb + byte);
            acc2 = __builtin_amdgcn_mfma_f32_16x16x32_bf16(af, bfrag, acc2, 0, 0, 0);
        }
        #pragma unroll
        for (int r = 0; r < 4; ++r) {
            const int row = g * 4 + r;
            const int dd = d0 + cl;
            float v = acc2[r] * sinv[r];
            unsigned short hv = f2bf(v);
            size_t o = ((size_t)(b * N_) + i0 + row) * D_ + h * HD_ + dd;
            avh[o] = hv;
            avl[o] = f2bf(v - bf2f(hv));
        }
    }
}

extern "C" void kernel_launch(void* const* d_in, const int* in_sizes, int n_in,
                              void* d_out, int out_size, void* d_ws, size_t ws_size,
                              hipStream_t stream) {
    (void)in_sizes; (void)n_in; (void)out_size; (void)ws_size;
    const float* x      = (const float*)d_in[0];
    const float* coords = (const float*)d_in[1];
    const unsigned char* kpm = (const unsigned char*)d_in[2];
    const float* alpha  = (const float*)d_in[3];
    const float* W1     = (const float*)d_in[4];
    const float* b1     = (const float*)d_in[5];
    const float* W2     = (const float*)d_in[6];
    const float* b2     = (const float*)d_in[7];
    const float* Wqkv   = (const float*)d_in[8];
    const float* Wout   = (const float*)d_in[9];
    const float* bout   = (const float*)d_in[10];

    float* out  = (float*)d_out;                     // [B,N,D]
    float* attn = out + (size_t)B_ * N_ * D_;        // [B,H,N,N] (pure output)

    char* w = (char*)d_ws;
    auto alloc = [&](size_t bytes) { char* p = w; w += (bytes + 255) & ~(size_t)255; return p; };
    const size_t SZ_X  = (size_t)B_ * N_ * D_;
    const size_t SZ_WQ = (size_t)3 * D_ * D_;
    const size_t SZ_WO = (size_t)D_ * D_;

    // long-lived
    unsigned short* wo_hi = (unsigned short*)alloc(SZ_WO * 2);
    unsigned short* wo_lo = (unsigned short*)alloc(SZ_WO * 2);
    unsigned short* qp = (unsigned short*)alloc((size_t)B_ * H_ * N_ * 128 * 2);
    unsigned short* kp = (unsigned short*)alloc((size_t)B_ * H_ * N_ * 128 * 2);
    unsigned short* vT = (unsigned short*)alloc((size_t)B_ * H_ * HD_ * N_ * 2);
    unsigned short* av_hi = (unsigned short*)alloc(SZ_X * 2);
    unsigned short* av_lo = (unsigned short*)alloc(SZ_X * 2);
    unsigned short* Pt = (unsigned short*)alloc((size_t)32 * B_ * N_ * 2);   // 256 KB
    int* flag = (int*)alloc(256);

    // union region: stage-1 (x/wq staging + qkv) vs stage-2 (f16 bias)
    char* uni = (char*)alloc(0);
    unsigned short* x_hi = (unsigned short*)uni;
    unsigned short* x_lo = x_hi + SZ_X;
    unsigned short* wq_hi = x_lo + SZ_X;
    unsigned short* wq_lo = wq_hi + SZ_WQ;
    float* qkv = (float*)(wq_lo + SZ_WQ);
    unsigned short* biasH = (unsigned short*)uni;     // 67 MB, aliases stage-1

    k_split<<<(int)((SZ_X + 255) / 256), 256, 0, stream>>>(x, x_hi, x_lo, (int)SZ_X);
    k_split<<<(int)((SZ_WQ + 255) / 256), 256, 0, stream>>>(Wqkv, wq_hi, wq_lo, (int)SZ_WQ);
    k_split<<<(int)((SZ_WO + 255) / 256), 256, 0, stream>>>(Wout, wo_hi, wo_lo, (int)SZ_WO);
    k_mask_detect<<<1, 256, 0, stream>>>(kpm, flag);
    k_nodeproj<<<(32 * B_ * N_) / 256, 256, 0, stream>>>(coords, W1, Pt);
    k_gemm3<<<dim3(64, 12), 256, 0, stream>>>(x_hi, x_lo, wq_hi, wq_lo, qkv, nullptr,
                                              B_ * N_, 3 * D_, D_);
    k_rearrange<<<(B_ * H_ * N_ * HD_) / 256, 256, 0, stream>>>(qkv, qp, kp);
    k_vtrans<<<dim3(16, H_, B_), 256, 0, stream>>>(qkv, vT);
    k_bias<<<(B_ * N_ * N_) / 256, 256, 0, stream>>>(coords, alpha, W1, b1, W2, b2, Pt, biasH);
    k_attn<<<dim3(64, H_, B_), 256, 0, stream>>>(qp, kp, vT, biasH, attn, kpm, flag, av_hi, av_lo);
    k_gemm3<<<dim3(64, 4), 256, 0, stream>>>(av_hi, av_lo, wo_hi, wo_lo, out, bout,
                                             B_ * N_, D_, D_);
}

// Round 20
// 235.584 us; speedup vs baseline: 1.1261x; 1.0056x over previous
//
#include <hip/hip_runtime.h>
#include <hip/hip_fp16.h>
#include <stdint.h>
#include <math.h>

#define B_  4
#define N_  1024
#define D_  512
#define H_  8
#define HD_ 64

typedef short s16x8 __attribute__((ext_vector_type(8)));
typedef float f32x4 __attribute__((ext_vector_type(4)));
typedef float f32x2 __attribute__((ext_vector_type(2)));
typedef __fp16 f16x2 __attribute__((ext_vector_type(2)));
typedef __fp16 f16x8 __attribute__((ext_vector_type(8)));

typedef const __attribute__((address_space(1))) void* gas1p;
typedef __attribute__((address_space(3))) void* las3p;
__device__ __forceinline__ void gload16(const void* g, void* l) {
    __builtin_amdgcn_global_load_lds((gas1p)g, (las3p)l, 16, 0, 0);
}

__device__ __forceinline__ unsigned short f2bf(float f) {
    unsigned u = __float_as_uint(f);
    u += 0x7fffu + ((u >> 16) & 1u);      // RNE
    return (unsigned short)(u >> 16);
}
__device__ __forceinline__ float bf2f(unsigned short h) {
    return __uint_as_float(((unsigned)h) << 16);
}

// fast exact-erf gelu: A&S 7.1.26 rational, |erf err| <= 1.5e-7, branch-free
__device__ __forceinline__ float fast_gelu(float x) {
    float ax = fabsf(x) * 0.7071067811865476f;          // |x|/sqrt(2)
    float t  = __builtin_amdgcn_rcpf(fmaf(0.3275911f, ax, 1.0f));
    float e  = __expf(-ax * ax);
    float poly = t * fmaf(t, fmaf(t, fmaf(t, fmaf(t, 1.061405429f, -1.453152027f),
                                          1.421413741f), -0.284496736f), 0.254829592f);
    float erfv = 1.0f - poly * e;                        // erf(|x|/sqrt2)
    float s = copysignf(erfv, x);
    return 0.5f * x * (1.0f + s);
}

// ---------------- split f32 -> (hi, lo) bf16 ----------------
__global__ void k_split(const float* __restrict__ s, unsigned short* __restrict__ h,
                        unsigned short* __restrict__ l, int n) {
    int i = blockIdx.x * 256 + threadIdx.x;
    if (i < n) {
        float x = s[i];
        unsigned short hb = f2bf(x);
        h[i] = hb;
        l[i] = f2bf(x - bf2f(hb));
    }
}

// ---------------- mask layout detection ----------------
__global__ void k_mask_detect(const unsigned char* __restrict__ m, int* __restrict__ flag) {
    __shared__ int s;
    if (threadIdx.x == 0) s = 0;
    __syncthreads();
    int found = 0;
    for (int i = threadIdx.x; i < B_ * N_; i += 256)
        if ((i & 3) && m[i]) found = 1;
    if (found) atomicOr(&s, 1);
    __syncthreads();
    if (threadIdx.x == 0) flag[0] = s;
}

// ---------------- split-bf16 GEMM: C[M,N] = A[M,K] @ B[N,K]^T (+bias) ----------------
__global__ __launch_bounds__(256) void k_gemm3(
    const unsigned short* __restrict__ Ah, const unsigned short* __restrict__ Al,
    const unsigned short* __restrict__ Bwh, const unsigned short* __restrict__ Bwl,
    float* __restrict__ C, const float* __restrict__ bias, int M, int Nn, int K)
{
    constexpr int BM = 64, BN = 128, BK = 64;
    __shared__ unsigned short At[BM * BK];
    __shared__ unsigned short Bt[BN * BK];
    const int tid = threadIdx.x, lane = tid & 63, wid = tid >> 6;
    const int m0 = blockIdx.x * BM, n0 = blockIdx.y * BN;
    const int wm = wid >> 1, wn = wid & 1;   // wave tile: 32 rows x 64 cols
    f32x4 acc[2][4] = {};
    const unsigned short* Aps[3] = {Ah, Ah, Al};
    const unsigned short* Bps[3] = {Bwh, Bwl, Bwh};

    for (int combo = 0; combo < 3; ++combo) {
        const unsigned short* __restrict__ Ap = Aps[combo];
        const unsigned short* __restrict__ Bp = Bps[combo];
        for (int k0 = 0; k0 < K; k0 += BK) {
            __syncthreads();  // previous-iter LDS reads done before DMA overwrite
            #pragma unroll
            for (int r = 0; r < 2; ++r) {
                int s = r * 256 + tid, row = s >> 3, c8 = s & 7;
                gload16(Ap + (size_t)(m0 + row) * K + k0 + c8 * 8, At + s * 8);
            }
            #pragma unroll
            for (int r = 0; r < 4; ++r) {
                int s = r * 256 + tid, row = s >> 3, c8 = s & 7;
                gload16(Bp + (size_t)(n0 + row) * K + k0 + c8 * 8, Bt + s * 8);
            }
            __syncthreads();  // drains vmcnt -> tiles ready
            #pragma unroll
            for (int kk = 0; kk < BK; kk += 32) {
                s16x8 a[2], bb[4];
                #pragma unroll
                for (int fm = 0; fm < 2; ++fm)
                    a[fm] = *(const s16x8*)(At + (wm * 32 + fm * 16 + (lane & 15)) * BK + kk + (lane >> 4) * 8);
                #pragma unroll
                for (int fn = 0; fn < 4; ++fn)
                    bb[fn] = *(const s16x8*)(Bt + (wn * 64 + fn * 16 + (lane & 15)) * BK + kk + (lane >> 4) * 8);
                #pragma unroll
                for (int fm = 0; fm < 2; ++fm)
                    #pragma unroll
                    for (int fn = 0; fn < 4; ++fn)
                        acc[fm][fn] = __builtin_amdgcn_mfma_f32_16x16x32_bf16(a[fm], bb[fn], acc[fm][fn], 0, 0, 0);
            }
        }
    }
    #pragma unroll
    for (int fm = 0; fm < 2; ++fm)
        #pragma unroll
        for (int fn = 0; fn < 4; ++fn)
            #pragma unroll
            for (int r = 0; r < 4; ++r) {
                int row  = m0 + wm * 32 + fm * 16 + (lane >> 4) * 4 + r;
                int coln = n0 + wn * 64 + fn * 16 + (lane & 15);
                float v = acc[fm][fn][r];
                if (bias) v += bias[coln];
                C[(size_t)row * Nn + coln] = v;
            }
}

// ---------------- rearrange qkv -> q'=[qh|ql], k'=[kh|kl] bf16 [B,H,N,128] ----------------
__global__ void k_rearrange(const float* __restrict__ qkv, unsigned short* __restrict__ qp,
                            unsigned short* __restrict__ kp) {
    int t = blockIdx.x * 256 + threadIdx.x;
    int d = t & 63, n = (t >> 6) & 1023, h = (t >> 16) & 7, b = t >> 19;
    const float* src = qkv + ((size_t)(b * N_ + n)) * (3 * D_) + h * HD_ + d;
    float q = src[0], k = src[D_];
    unsigned short qh = f2bf(q), ql = f2bf(q - bf2f(qh));
    unsigned short kh = f2bf(k), kl = f2bf(k - bf2f(kh));
    size_t base = ((size_t)(b * H_ + h) * N_ + n) * 128;
    qp[base + d] = qh; qp[base + 64 + d] = ql;
    kp[base + d] = kh; kp[base + 64 + d] = kl;
}

// ---------------- v -> vT bf16 [B,H,HD,N] (LDS transpose) ----------------
__global__ void k_vtrans(const float* __restrict__ qkv, unsigned short* __restrict__ vT) {
    __shared__ unsigned short T[64][65];
    int n0 = blockIdx.x * 64, h = blockIdx.y, b = blockIdx.z;
    int tid = threadIdx.x;
    #pragma unroll
    for (int rep = 0; rep < 16; ++rep) {
        int idx = rep * 256 + tid;
        int nl = idx >> 6, d = idx & 63;
        T[nl][d] = f2bf(qkv[((size_t)(b * N_ + n0 + nl)) * (3 * D_) + 2 * D_ + h * HD_ + d]);
    }
    __syncthreads();
    #pragma unroll
    for (int rep = 0; rep < 16; ++rep) {
        int idx = rep * 256 + tid;
        int dl = idx >> 6, nl = idx & 63;
        vT[((size_t)(b * H_ + h) * HD_ + dl) * N_ + n0 + nl] = T[nl][dl];
    }
}

// ---------------- per-node projection table, pair-major: PtT[bn][32] f16 (x32 prescale) ----------------
__global__ void k_nodeproj(const float* __restrict__ coords, const float* __restrict__ W1,
                           unsigned short* __restrict__ PtT) {
    int bn = blockIdx.x * 256 + threadIdx.x;         // 4096 nodes
    const float* cc = coords + (size_t)bn * 3;
    float c0 = cc[0], c1 = cc[1], c2 = cc[2];
    unsigned short outv[32];
    #pragma unroll
    for (int c = 0; c < 32; ++c) {
        float v = 32.f * (W1[c * 4] * c0 + W1[c * 4 + 1] * c1 + W1[c * 4 + 2] * c2);
        __half hv = __float2half(v);
        outv[c] = *(unsigned short*)&hv;
    }
    #pragma unroll
    for (int k = 0; k < 4; ++k)
        *(s16x8*)(PtT + (size_t)bn * 32 + k * 8) = *(const s16x8*)(outv + k * 8);
}

// ---------------- pairwise MLP bias -> f16 [B,H,N,N] ----------------
// Layer-1 + LUT gelu built straight into MFMA A-fragments (lane l: pairs m*16+(l&15),
// channels (l>>4)*8..+7); layer-2 = one mfma_f32_16x16x32_f16 per 16 pairs (B = W2 f16,
// heads 0-7, zero-padded cols 8-15). C row=pair, col=head -> packed 8B f16 stores.
__global__ __launch_bounds__(256) void k_bias(
    const float* __restrict__ coords, const float* __restrict__ alpha,
    const float* __restrict__ W1, const float* __restrict__ b1,
    const float* __restrict__ W2, const float* __restrict__ b2,
    const unsigned short* __restrict__ PtT,   // f16 [B*N][32], prescaled x32
    unsigned short* __restrict__ biasH)
{
    __shared__ unsigned short sPj[256 * 40];   // 20 KB: [pair][32ch] padded to 40
    __shared__ float lut[512];                 // 256 x (val, slope)
    __shared__ float SPi[32], swd32[32], sb2f[8];
    __shared__ float sdist[256];
    const int tid = threadIdx.x, lane = tid & 63, wid = tid >> 6;
    const int bid = blockIdx.x;
    const int j0 = (bid & 3) * 256;
    const int i  = (bid >> 2) & 1023;
    const int b  = bid >> 12;

    // LUT build: x_k = (k-128)/32
    {
        float xk = (tid - 128) * 0.03125f;
        float g0 = fast_gelu(xk);
        float g1 = fast_gelu(xk + 0.03125f);
        lut[tid * 2]     = g0;
        lut[tid * 2 + 1] = g1 - g0;
    }
    if (tid < 32) {
        const float* ci = coords + ((size_t)b * N_ + i) * 3;
        float w0 = W1[tid * 4], w1 = W1[tid * 4 + 1], w2 = W1[tid * 4 + 2], w3 = W1[tid * 4 + 3];
        SPi[tid]   = 32.f * (w0 * ci[0] + w1 * ci[1] + w2 * ci[2] + b1[tid]) + 128.f;
        swd32[tid] = 32.f * w3;
    }
    if (tid < 8) sb2f[tid] = b2[tid];
    {   // stage PtT slice [j0..j0+255][32] -> sPj (pad 40), linear global reads
        const unsigned short* src = PtT + ((size_t)(b * N_) + j0) * 32;
        #pragma unroll
        for (int k = 0; k < 4; ++k) {
            int idx = k * 256 + tid;               // 1024 chunks of 8 u16
            *(s16x8*)(sPj + (idx >> 2) * 40 + (idx & 3) * 8) = *(const s16x8*)(src + idx * 8);
        }
    }
    // dist for own pair
    {
        const float* ci = coords + ((size_t)b * N_ + i) * 3;
        const float* cj = coords + ((size_t)b * N_ + j0 + tid) * 3;
        float dx = ci[0] - cj[0], dy = ci[1] - cj[1], dz = ci[2] - cj[2];
        sdist[tid] = sqrtf(dx * dx + dy * dy + dz * dz);
    }
    __syncthreads();

    const int hh = lane & 15;                  // head (cols 8-15 are padding)
    const int q  = lane >> 4;                  // k-oct
    const float alph = alpha[0];
    const float vfi = (i >= 1) ? 1.f : 0.f;

    // B fragment: W2[hh][q*8..+7] as f16 (zero rows for hh>=8)
    f16x8 bw;
    {
        int hw = hh & 7;
        #pragma unroll
        for (int e = 0; e < 8; ++e) {
            float wv = W2[hw * 32 + q * 8 + e];
            bw[e] = (hh < 8) ? (__fp16)wv : (__fp16)0.f;
        }
    }

    #pragma unroll 1
    for (int m = 0; m < 4; ++m) {
        const int pm = m * 16 + hh;            // wave-local pair for A row
        const float dist = sdist[wid * 64 + pm];
        s16x8 praw = *(const s16x8*)(sPj + (wid * 64 + pm) * 40 + q * 8);
        f16x8 af;
        #pragma unroll
        for (int e = 0; e < 8; ++e) {
            int c = q * 8 + e;
            unsigned short u = (unsigned short)praw[e];
            float pj = __half2float(*(const __half*)&u);
            float t  = fmaf(swd32[c], dist, SPi[c] - pj);   // table coordinate
            float tc = fminf(fmaxf(t, 0.f), 255.f);
            float fi = floorf(tc);
            int   ii = (int)fi;
            float fr = tc - fi;
            f32x2 vs = *(const f32x2*)(lut + ii * 2);
            float gg = fmaf(fr, vs[1], vs[0]);
            float xb = fmaf(t, 0.03125f, -4.f);             // x, for overflow
            gg = (t > 254.f) ? xb : gg;
            af[e] = (__fp16)gg;
        }
        f32x4 c4 = {0.f, 0.f, 0.f, 0.f};
        c4 = __builtin_amdgcn_mfma_f32_16x16x32_f16(af, bw, c4, 0, 0, 0);
        if (hh < 8) {
            const int jb = j0 + wid * 64 + m * 16 + q * 4;   // C rows = pairs q*4+r
            const float b2h = sb2f[hh];
            float v0 = ((jb     >= 1) ? alph : 0.f) * vfi * (c4[0] + b2h);
            float v1 = ((jb + 1 >= 1) ? alph : 0.f) * vfi * (c4[1] + b2h);
            float v2 = ((jb + 2 >= 1) ? alph : 0.f) * vfi * (c4[2] + b2h);
            float v3 = ((jb + 3 >= 1) ? alph : 0.f) * vfi * (c4[3] + b2h);
            __half h0 = __float2half(v0), h1 = __float2half(v1);
            __half h2 = __float2half(v2), h3 = __float2half(v3);
            unsigned int lo = (unsigned)*(unsigned short*)&h0 | ((unsigned)*(unsigned short*)&h1 << 16);
            unsigned int hi = (unsigned)*(unsigned short*)&h2 | ((unsigned)*(unsigned short*)&h3 << 16);
            unsigned long long pk = (unsigned long long)lo | ((unsigned long long)hi << 32);
            *(unsigned long long*)(biasH + ((size_t)(b * H_ + hh) * N_ + i) * N_ + jb) = pk;
        }
    }
}

// ---------------- fused attention: DMA-staged K dots + register logits ----------------
__global__ __launch_bounds__(256, 4) void k_attn(
    const unsigned short* __restrict__ qp, const unsigned short* __restrict__ kp,
    const unsigned short* __restrict__ vT,
    const unsigned short* __restrict__ biasH,   // f16 [B,H,N,N]
    float* __restrict__ attnout,                // f32 [B,H,N,N] (pure output)
    const unsigned char* __restrict__ mraw, const int* __restrict__ flag,
    unsigned short* __restrict__ avh, unsigned short* __restrict__ avl)  // [B,N,D] hi/lo
{
    __shared__ s16x8 pool16[2048];            // 32 KB: K dbuf -> bias tile -> P
    __shared__ unsigned char smask[N_];
    __shared__ float redm[16][4];
    __shared__ float reds[16][4];
    const int tid = threadIdx.x, lane = tid & 63, wid = tid >> 6;

    // XCD-aware swizzle (bijective: 2048 % 8 == 0)
    int flat = blockIdx.x + 64 * (blockIdx.y + 8 * blockIdx.z);
    int swz  = (flat & 7) * 256 + (flat >> 3);
    const int i0 = (swz & 63) * 16;
    const int h  = (swz >> 6) & 7;
    const int b  = swz >> 9;
    const size_t bh = (size_t)(b * H_ + h);
    const int g = lane >> 4;                  // quad group 0..3
    const int cl = lane & 15;                 // col-lane

    if (flag[0] != 0) {
        for (int i2 = tid; i2 < N_; i2 += 256) smask[i2] = mraw[b * N_ + i2];
    } else {
        const int* mi = (const int*)mraw;
        for (int i2 = tid; i2 < N_; i2 += 256) smask[i2] = (unsigned char)(mi[b * N_ + i2] != 0);
    }

    // q fragments: rows i0+cl, layout [qh(64)|ql(64)]
    const unsigned short* qrow = qp + (bh * N_ + i0 + cl) * 128 + g * 8;
    s16x8 aqh0 = *(const s16x8*)(qrow);
    s16x8 aqh1 = *(const s16x8*)(qrow + 32);
    s16x8 aql0 = *(const s16x8*)(qrow + 64);
    s16x8 aql1 = *(const s16x8*)(qrow + 96);

    // staging source offsets (chunk-relative, XOR-swizzled source; LDS dest linear)
    int soff[4];
    #pragma unroll
    for (int p = 0; p < 4; ++p) {
        int o = p * 4096 + tid * 16;
        int row = o >> 8, offl = o & 255;
        soff[p] = row * 128 + ((offl ^ ((row & 7) << 4)) >> 1);
    }
    const unsigned short* kbase = kp + bh * (size_t)N_ * 128;

    const int lr = wid * 16 + cl;
    int rdoff[4];
    #pragma unroll
    for (int f = 0; f < 4; ++f)
        rdoff[f] = lr * 256 + ((g * 16 + f * 64) ^ ((lr & 7) << 4));

    char* poolb = (char*)pool16;

    // stage chunk 0 via DMA
    #pragma unroll
    for (int p = 0; p < 4; ++p)
        gload16(kbase + soff[p], poolb + p * 4096 + tid * 16);
    __syncthreads();

    // pipelined chunk loop: issue DMA for c+1 -> compute c -> barrier (drains vmcnt)
    f32x4 acc[16];
    #pragma unroll
    for (int c = 0; c < 16; ++c) {
        if (c < 15) {
            const unsigned short* cb = kbase + (size_t)(c + 1) * 8192;
            char* wb = poolb + ((c + 1) & 1) * 16384;
            #pragma unroll
            for (int p = 0; p < 4; ++p)
                gload16(cb + soff[p], wb + p * 4096 + tid * 16);
        }
        char* kb = poolb + (c & 1) * 16384;
        s16x8 k0 = *(const s16x8*)(kb + rdoff[0]);
        s16x8 k1 = *(const s16x8*)(kb + rdoff[1]);
        s16x8 k2 = *(const s16x8*)(kb + rdoff[2]);
        s16x8 k3 = *(const s16x8*)(kb + rdoff[3]);
        f32x4 a = {0.f, 0.f, 0.f, 0.f};
        a = __builtin_amdgcn_mfma_f32_16x16x32_bf16(aqh0, k0, a, 0, 0, 0);
        a = __builtin_amdgcn_mfma_f32_16x16x32_bf16(aqh1, k1, a, 0, 0, 0);
        a = __builtin_amdgcn_mfma_f32_16x16x32_bf16(aqh0, k2, a, 0, 0, 0);
        a = __builtin_amdgcn_mfma_f32_16x16x32_bf16(aqh1, k3, a, 0, 0, 0);
        a = __builtin_amdgcn_mfma_f32_16x16x32_bf16(aql0, k0, a, 0, 0, 0);
        a = __builtin_amdgcn_mfma_f32_16x16x32_bf16(aql1, k1, a, 0, 0, 0);
        acc[c] = a;
        __syncthreads();
    }

    // bias tile: DMA copy 32 KB global f16 -> pool (K data dead)
    {
        const unsigned short* bsrc = biasH + (bh * N_ + i0) * N_;
        unsigned short* bl = (unsigned short*)poolb;
        #pragma unroll
        for (int p2 = 0; p2 < 8; ++p2) {
            int idx = p2 * 256 + tid;
            gload16(bsrc + (size_t)idx * 8, bl + idx * 8);
        }
    }
    __syncthreads();

    // logits: scale + bias + mask (col = (j*4+wid)*16 + cl)
    const float scale = 0.125f;               // HD^-0.5
    const unsigned short* bl = (const unsigned short*)poolb;
    #pragma unroll
    for (int j = 0; j < 16; ++j) {
        const int col = (j * 4 + wid) * 16 + cl;
        const bool mj = (smask[col] != 0);
        #pragma unroll
        for (int r = 0; r < 4; ++r) {
            unsigned short u = bl[(g * 4 + r) * 1024 + col];
            float bv = __half2float(*(const __half*)&u);
            acc[j][r] = mj ? -1e30f : fmaf(acc[j][r], scale, bv);
        }
    }

    // row max
    float m[4];
    #pragma unroll
    for (int r = 0; r < 4; ++r) {
        float mm = acc[0][r];
        #pragma unroll
        for (int j = 1; j < 16; ++j) mm = fmaxf(mm, acc[j][r]);
        m[r] = mm;
    }
    #pragma unroll
    for (int msk = 1; msk < 16; msk <<= 1)
        #pragma unroll
        for (int r = 0; r < 4; ++r) m[r] = fmaxf(m[r], __shfl_xor(m[r], msk));
    if (cl == 0)
        #pragma unroll
        for (int r = 0; r < 4; ++r) redm[g * 4 + r][wid] = m[r];
    __syncthreads();
    #pragma unroll
    for (int r = 0; r < 4; ++r) {
        int row = g * 4 + r;
        m[r] = fmaxf(fmaxf(redm[row][0], redm[row][1]), fmaxf(redm[row][2], redm[row][3]));
    }

    // exp + row sum
    float s[4] = {0.f, 0.f, 0.f, 0.f};
    #pragma unroll
    for (int j = 0; j < 16; ++j)
        #pragma unroll
        for (int r = 0; r < 4; ++r) {
            float e = __expf(acc[j][r] - m[r]);
            acc[j][r] = e;
            s[r] += e;
        }
    #pragma unroll
    for (int msk = 1; msk < 16; msk <<= 1)
        #pragma unroll
        for (int r = 0; r < 4; ++r) s[r] += __shfl_xor(s[r], msk);
    if (cl == 0)
        #pragma unroll
        for (int r = 0; r < 4; ++r) reds[g * 4 + r][wid] = s[r];
    __syncthreads();
    float sinv[4];
    #pragma unroll
    for (int r = 0; r < 4; ++r) {
        int row = g * 4 + r;
        sinv[r] = 1.0f / (reds[row][0] + reds[row][1] + reds[row][2] + reds[row][3]);
    }

    // attn write (nontemporal) + P write (swizzled bf16; bias dead)
    float* gattn = attnout + (bh * N_ + i0) * N_;
    char* Pb = poolb;
    #pragma unroll
    for (int j = 0; j < 16; ++j) {
        const int col = (j * 4 + wid) * 16 + cl;
        #pragma unroll
        for (int r = 0; r < 4; ++r) {
            const int row = g * 4 + r;
            float e = acc[j][r];
            __builtin_nontemporal_store(e * sinv[r], &gattn[(size_t)row * N_ + col]);
            int byte = row * 2048 + ((col * 2) ^ ((row & 7) << 4));
            *(unsigned short*)(Pb + byte) = f2bf(e);
        }
    }
    __syncthreads();

    // PV
    {
        const int d0 = wid * 16;
        f32x4 acc2 = {0.f, 0.f, 0.f, 0.f};
        const unsigned short* vrow = vT + (bh * HD_ + d0 + cl) * N_ + g * 8;
        const int rowA = cl;
        const int swzb = (rowA & 7) << 4;
        for (int kk = 0; kk < N_; kk += 32) {
            s16x8 bfrag = *(const s16x8*)(vrow + kk);
            int byte = rowA * 2048 + (((kk + g * 8) * 2) ^ swzb);
            s16x8 af = *(const s16x8*)(Pb + byte);
            acc2 = __builtin_amdgcn_mfma_f32_16x16x32_bf16(af, bfrag, acc2, 0, 0, 0);
        }
        #pragma unroll
        for (int r = 0; r < 4; ++r) {
            const int row = g * 4 + r;
            const int dd = d0 + cl;
            float v = acc2[r] * sinv[r];
            unsigned short hv = f2bf(v);
            size_t o = ((size_t)(b * N_) + i0 + row) * D_ + h * HD_ + dd;
            avh[o] = hv;
            avl[o] = f2bf(v - bf2f(hv));
        }
    }
}

extern "C" void kernel_launch(void* const* d_in, const int* in_sizes, int n_in,
                              void* d_out, int out_size, void* d_ws, size_t ws_size,
                              hipStream_t stream) {
    (void)in_sizes; (void)n_in; (void)out_size; (void)ws_size;
    const float* x      = (const float*)d_in[0];
    const float* coords = (const float*)d_in[1];
    const unsigned char* kpm = (const unsigned char*)d_in[2];
    const float* alpha  = (const float*)d_in[3];
    const float* W1     = (const float*)d_in[4];
    const float* b1     = (const float*)d_in[5];
    const float* W2     = (const float*)d_in[6];
    const float* b2     = (const float*)d_in[7];
    const float* Wqkv   = (const float*)d_in[8];
    const float* Wout   = (const float*)d_in[9];
    const float* bout   = (const float*)d_in[10];

    float* out  = (float*)d_out;                     // [B,N,D]
    float* attn = out + (size_t)B_ * N_ * D_;        // [B,H,N,N] (pure output)

    char* w = (char*)d_ws;
    auto alloc = [&](size_t bytes) { char* p = w; w += (bytes + 255) & ~(size_t)255; return p; };
    const size_t SZ_X  = (size_t)B_ * N_ * D_;
    const size_t SZ_WQ = (size_t)3 * D_ * D_;
    const size_t SZ_WO = (size_t)D_ * D_;

    // long-lived
    unsigned short* wo_hi = (unsigned short*)alloc(SZ_WO * 2);
    unsigned short* wo_lo = (unsigned short*)alloc(SZ_WO * 2);
    unsigned short* qp = (unsigned short*)alloc((size_t)B_ * H_ * N_ * 128 * 2);
    unsigned short* kp = (unsigned short*)alloc((size_t)B_ * H_ * N_ * 128 * 2);
    unsigned short* vT = (unsigned short*)alloc((size_t)B_ * H_ * HD_ * N_ * 2);
    unsigned short* av_hi = (unsigned short*)alloc(SZ_X * 2);
    unsigned short* av_lo = (unsigned short*)alloc(SZ_X * 2);
    unsigned short* PtT = (unsigned short*)alloc((size_t)B_ * N_ * 32 * 2);   // 256 KB, pair-major
    int* flag = (int*)alloc(256);

    // union region: stage-1 (x/wq staging + qkv) vs stage-2 (f16 bias)
    char* uni = (char*)alloc(0);
    unsigned short* x_hi = (unsigned short*)uni;
    unsigned short* x_lo = x_hi + SZ_X;
    unsigned short* wq_hi = x_lo + SZ_X;
    unsigned short* wq_lo = wq_hi + SZ_WQ;
    float* qkv = (float*)(wq_lo + SZ_WQ);
    unsigned short* biasH = (unsigned short*)uni;     // 67 MB, aliases stage-1

    k_split<<<(int)((SZ_X + 255) / 256), 256, 0, stream>>>(x, x_hi, x_lo, (int)SZ_X);
    k_split<<<(int)((SZ_WQ + 255) / 256), 256, 0, stream>>>(Wqkv, wq_hi, wq_lo, (int)SZ_WQ);
    k_split<<<(int)((SZ_WO + 255) / 256), 256, 0, stream>>>(Wout, wo_hi, wo_lo, (int)SZ_WO);
    k_mask_detect<<<1, 256, 0, stream>>>(kpm, flag);
    k_nodeproj<<<(B_ * N_) / 256, 256, 0, stream>>>(coords, W1, PtT);
    k_gemm3<<<dim3(64, 12), 256, 0, stream>>>(x_hi, x_lo, wq_hi, wq_lo, qkv, nullptr,
                                              B_ * N_, 3 * D_, D_);
    k_rearrange<<<(B_ * H_ * N_ * HD_) / 256, 256, 0, stream>>>(qkv, qp, kp);
    k_vtrans<<<dim3(16, H_, B_), 256, 0, stream>>>(qkv, vT);
    k_bias<<<(B_ * N_ * N_) / 256, 256, 0, stream>>>(coords, alpha, W1, b1, W2, b2, PtT, biasH);
    k_attn<<<dim3(64, H_, B_), 256, 0, stream>>>(qp, kp, vT, biasH, attn, kpm, flag, av_hi, av_lo);
    k_gemm3<<<dim3(64, 4), 256, 0, stream>>>(av_hi, av_lo, wo_hi, wo_lo, out, bout,
                                             B_ * N_, D_, D_);
}